// Round 1
// baseline (3538.596 us; speedup 1.0000x reference)
//
#include <hip/hip_runtime.h>

#define NUSERS 200000
#define NITEMS 100000
#define NNODES 300000
#define EDIM   64
#define NEDGES 2000000

// Layer-1 scatter: reads source rows directly from the (virtually concatenated)
// u/i embedding arrays. 16 threads per edge, each handles one float4 (4 dims).
__global__ void scatter_l1(const float* __restrict__ u, const float* __restrict__ it,
                           float* __restrict__ y,
                           const int* __restrict__ src, const int* __restrict__ dst,
                           const float* __restrict__ w) {
    long long t = (long long)blockIdx.x * blockDim.x + threadIdx.x;
    int e = (int)(t >> 4);
    if (e >= NEDGES) return;
    int q = (int)(t & 15);
    int s = src[e];
    int d = dst[e];
    float we = w[e];
    const float* xrow = (s < NUSERS) ? (u + (size_t)s * EDIM)
                                     : (it + (size_t)(s - NUSERS) * EDIM);
    float4 v = ((const float4*)xrow)[q];
    float* yp = y + (size_t)d * EDIM + q * 4;
    atomicAdd(yp + 0, we * v.x);
    atomicAdd(yp + 1, we * v.y);
    atomicAdd(yp + 2, we * v.z);
    atomicAdd(yp + 3, we * v.w);
}

// Generic scatter: x -> y (layer 2: x = x1 in d_out, y = x2 in d_ws)
__global__ void scatter_gen(const float* __restrict__ x, float* __restrict__ y,
                            const int* __restrict__ src, const int* __restrict__ dst,
                            const float* __restrict__ w) {
    long long t = (long long)blockIdx.x * blockDim.x + threadIdx.x;
    int e = (int)(t >> 4);
    if (e >= NEDGES) return;
    int q = (int)(t & 15);
    int s = src[e];
    int d = dst[e];
    float we = w[e];
    float4 v = ((const float4*)(x + (size_t)s * EDIM))[q];
    float* yp = y + (size_t)d * EDIM + q * 4;
    atomicAdd(yp + 0, we * v.x);
    atomicAdd(yp + 1, we * v.y);
    atomicAdd(yp + 2, we * v.z);
    atomicAdd(yp + 3, we * v.w);
}

// out = (x0 + x1 + x2) / 3, where x0 is re-gathered from u/i, x1 = out, x2 = A
__global__ void final_kernel(const float4* __restrict__ u, const float4* __restrict__ it,
                             const float4* __restrict__ x2, float4* __restrict__ outq) {
    int i = blockIdx.x * blockDim.x + threadIdx.x;
    const int uq = NUSERS * EDIM / 4;
    const int nq = NNODES * EDIM / 4;
    if (i >= nq) return;
    float4 x0 = (i < uq) ? u[i] : it[i - uq];
    float4 x1 = outq[i];
    float4 a  = x2[i];
    const float s = 1.0f / 3.0f;
    float4 r;
    r.x = (x0.x + x1.x + a.x) * s;
    r.y = (x0.y + x1.y + a.y) * s;
    r.z = (x0.z + x1.z + a.z) * s;
    r.w = (x0.w + x1.w + a.w) * s;
    outq[i] = r;
}

extern "C" void kernel_launch(void* const* d_in, const int* in_sizes, int n_in,
                              void* d_out, int out_size, void* d_ws, size_t ws_size,
                              hipStream_t stream) {
    const float* u  = (const float*)d_in[0];
    const float* it = (const float*)d_in[1];
    const int*   src = (const int*)d_in[2];
    const int*   dst = (const int*)d_in[3];
    const float* w   = (const float*)d_in[4];
    float* out = (float*)d_out;
    float* A   = (float*)d_ws;   // x2 buffer, NNODES*EDIM floats = 76.8 MB

    const size_t nd = (size_t)NNODES * EDIM;
    const int nq = NNODES * EDIM / 4;
    dim3 blk(256);

    // x1 accumulation target = d_out; zero it (harness poisons with 0xAA)
    hipMemsetAsync(out, 0, nd * sizeof(float), stream);

    long long nthreads = (long long)NEDGES * 16;
    int sblocks = (int)((nthreads + 255) / 256);

    // layer 1: x1[dst] += w * x0[src]  (x0 read directly from u/i)
    scatter_l1<<<sblocks, blk, 0, stream>>>(u, it, out, src, dst, w);

    // zero x2 buffer
    hipMemsetAsync(A, 0, nd * sizeof(float), stream);

    // layer 2: x2[dst] += w * x1[src]
    scatter_gen<<<sblocks, blk, 0, stream>>>(out, A, src, dst, w);

    // out = (x0 + x1 + x2) / 3
    final_kernel<<<(nq + 255) / 256, blk, 0, stream>>>(
        (const float4*)u, (const float4*)it, (const float4*)A, (float4*)out);
}

// Round 2
// 797.265 us; speedup vs baseline: 4.4384x; 4.4384x over previous
//
#include <hip/hip_runtime.h>

#define NUSERS 200000
#define NITEMS 100000
#define NNODES 300000
#define EDIM   64
#define NEDGES 2000000
#define SCAN_NB ((NNODES + 255) / 256)   // 1172 blocks

// ---------------- CSR build (counting sort by dst) ----------------

__global__ void k_hist(const int* __restrict__ dst, int* __restrict__ cnt) {
    int e = blockIdx.x * 256 + threadIdx.x;
    if (e < NEDGES) atomicAdd(&cnt[dst[e]], 1);
}

// in-place exclusive scan of 256-element chunks; block totals to bsum
__global__ void k_scan1(int* __restrict__ data, int* __restrict__ bsum) {
    __shared__ int s[256];
    int i = blockIdx.x * 256 + threadIdx.x;
    int v = (i < NNODES) ? data[i] : 0;
    s[threadIdx.x] = v;
    __syncthreads();
    for (int o = 1; o < 256; o <<= 1) {
        int t = (threadIdx.x >= o) ? s[threadIdx.x - o] : 0;
        __syncthreads();
        s[threadIdx.x] += t;
        __syncthreads();
    }
    if (i < NNODES) data[i] = s[threadIdx.x] - v;          // exclusive
    if (threadIdx.x == 255) bsum[blockIdx.x] = s[255];     // inclusive total
}

// single-block exclusive scan over SCAN_NB block totals (with running carry)
__global__ void k_scan2(int* __restrict__ bsum) {
    __shared__ int s[256];
    __shared__ int carry;
    if (threadIdx.x == 0) carry = 0;
    __syncthreads();
    for (int base = 0; base < SCAN_NB; base += 256) {
        int i = base + threadIdx.x;
        int v = (i < SCAN_NB) ? bsum[i] : 0;
        s[threadIdx.x] = v;
        __syncthreads();
        for (int o = 1; o < 256; o <<= 1) {
            int t = (threadIdx.x >= o) ? s[threadIdx.x - o] : 0;
            __syncthreads();
            s[threadIdx.x] += t;
            __syncthreads();
        }
        if (i < SCAN_NB) bsum[i] = s[threadIdx.x] - v + carry;
        __syncthreads();
        if (threadIdx.x == 0) carry += s[255];
        __syncthreads();
    }
}

__global__ void k_scan3(int* __restrict__ off, const int* __restrict__ bscan,
                        int* __restrict__ wpos) {
    int i = blockIdx.x * 256 + threadIdx.x;
    if (i < NNODES) {
        int v = off[i] + bscan[blockIdx.x];
        off[i] = v;
        wpos[i] = v;
    }
}

__global__ void k_fill(const int* __restrict__ src, const int* __restrict__ dst,
                       const float* __restrict__ w, int* __restrict__ wpos,
                       int* __restrict__ ssrc, float* __restrict__ sw) {
    int e = blockIdx.x * 256 + threadIdx.x;
    if (e < NEDGES) {
        int p = atomicAdd(&wpos[dst[e]], 1);
        ssrc[p] = src[e];
        sw[p] = w[e];
    }
}

// ---------------- gather SpMM: one wave per dst node, lane = dim ----------------

__global__ void k_spmm1(const float* __restrict__ u, const float* __restrict__ it,
                        const int* __restrict__ off, const int* __restrict__ ssrc,
                        const float* __restrict__ sw, float* __restrict__ x1) {
    int node = blockIdx.x * 4 + (threadIdx.x >> 6);
    int lane = threadIdx.x & 63;
    if (node >= NNODES) return;
    int p = off[node];
    int end = (node == NNODES - 1) ? NEDGES : off[node + 1];
    float acc = 0.f;
    for (; p < end; ++p) {
        int s = ssrc[p];
        float we = sw[p];
        const float* row = (s < NUSERS) ? (u + (size_t)s * EDIM)
                                        : (it + (size_t)(s - NUSERS) * EDIM);
        acc += we * row[lane];
    }
    x1[(size_t)node * EDIM + lane] = acc;
}

// layer-2 gather fused with final combine: out = (x0 + x1 + x2)/3
__global__ void k_spmm2(const float* __restrict__ u, const float* __restrict__ it,
                        const int* __restrict__ off, const int* __restrict__ ssrc,
                        const float* __restrict__ sw, const float* __restrict__ x1,
                        float* __restrict__ out) {
    int node = blockIdx.x * 4 + (threadIdx.x >> 6);
    int lane = threadIdx.x & 63;
    if (node >= NNODES) return;
    int p = off[node];
    int end = (node == NNODES - 1) ? NEDGES : off[node + 1];
    float acc = 0.f;
    for (; p < end; ++p) {
        acc += sw[p] * x1[(size_t)ssrc[p] * EDIM + lane];
    }
    size_t idx = (size_t)node * EDIM + lane;
    float x0 = (node < NUSERS) ? u[idx] : it[idx - (size_t)NUSERS * EDIM];
    out[idx] = (x0 + x1[idx] + acc) * (1.0f / 3.0f);
}

// ---------------- fallback (round-1 atomic path, if ws too small) ----------------

__global__ void scatter_l1(const float* __restrict__ u, const float* __restrict__ it,
                           float* __restrict__ y,
                           const int* __restrict__ src, const int* __restrict__ dst,
                           const float* __restrict__ w) {
    long long t = (long long)blockIdx.x * blockDim.x + threadIdx.x;
    int e = (int)(t >> 4);
    if (e >= NEDGES) return;
    int q = (int)(t & 15);
    int s = src[e], d = dst[e];
    float we = w[e];
    const float* xrow = (s < NUSERS) ? (u + (size_t)s * EDIM)
                                     : (it + (size_t)(s - NUSERS) * EDIM);
    float4 v = ((const float4*)xrow)[q];
    float* yp = y + (size_t)d * EDIM + q * 4;
    atomicAdd(yp + 0, we * v.x);
    atomicAdd(yp + 1, we * v.y);
    atomicAdd(yp + 2, we * v.z);
    atomicAdd(yp + 3, we * v.w);
}

__global__ void scatter_gen(const float* __restrict__ x, float* __restrict__ y,
                            const int* __restrict__ src, const int* __restrict__ dst,
                            const float* __restrict__ w) {
    long long t = (long long)blockIdx.x * blockDim.x + threadIdx.x;
    int e = (int)(t >> 4);
    if (e >= NEDGES) return;
    int q = (int)(t & 15);
    int s = src[e], d = dst[e];
    float we = w[e];
    float4 v = ((const float4*)(x + (size_t)s * EDIM))[q];
    float* yp = y + (size_t)d * EDIM + q * 4;
    atomicAdd(yp + 0, we * v.x);
    atomicAdd(yp + 1, we * v.y);
    atomicAdd(yp + 2, we * v.z);
    atomicAdd(yp + 3, we * v.w);
}

__global__ void final_kernel(const float4* __restrict__ u, const float4* __restrict__ it,
                             const float4* __restrict__ x2, float4* __restrict__ outq) {
    int i = blockIdx.x * blockDim.x + threadIdx.x;
    const int uq = NUSERS * EDIM / 4;
    const int nq = NNODES * EDIM / 4;
    if (i >= nq) return;
    float4 x0 = (i < uq) ? u[i] : it[i - uq];
    float4 x1 = outq[i];
    float4 a  = x2[i];
    const float s = 1.0f / 3.0f;
    float4 r;
    r.x = (x0.x + x1.x + a.x) * s;
    r.y = (x0.y + x1.y + a.y) * s;
    r.z = (x0.z + x1.z + a.z) * s;
    r.w = (x0.w + x1.w + a.w) * s;
    outq[i] = r;
}

// ---------------- launch ----------------

extern "C" void kernel_launch(void* const* d_in, const int* in_sizes, int n_in,
                              void* d_out, int out_size, void* d_ws, size_t ws_size,
                              hipStream_t stream) {
    const float* u   = (const float*)d_in[0];
    const float* it  = (const float*)d_in[1];
    const int*   src = (const int*)d_in[2];
    const int*   dst = (const int*)d_in[3];
    const float* w   = (const float*)d_in[4];
    float* out = (float*)d_out;

    const size_t nd = (size_t)NNODES * EDIM;

    // ws layout (full path)
    int*   off   = (int*)d_ws;              // NNODES
    int*   wpos  = off + NNODES;            // NNODES
    int*   bscan = wpos + NNODES;           // SCAN_NB (padded to 2048)
    int*   ssrc  = bscan + 2048;            // NEDGES
    float* sw    = (float*)(ssrc + NEDGES); // NEDGES
    float* x1    = sw + NEDGES;             // NNODES*EDIM
    const size_t needed =
        ((size_t)NNODES * 2 + 2048 + (size_t)NEDGES * 2 + nd) * sizeof(int);

    const int eb = (NEDGES + 255) / 256;        // 7813
    const int nb4 = (NNODES + 3) / 4;           // 75000 (one wave per node)
    dim3 blk(256);

    if (ws_size >= needed) {
        // --- CSR build ---
        hipMemsetAsync(off, 0, (size_t)NNODES * sizeof(int), stream);
        k_hist <<<eb, blk, 0, stream>>>(dst, off);
        k_scan1<<<SCAN_NB, blk, 0, stream>>>(off, bscan);
        k_scan2<<<1, blk, 0, stream>>>(bscan);
        k_scan3<<<SCAN_NB, blk, 0, stream>>>(off, bscan, wpos);
        k_fill <<<eb, blk, 0, stream>>>(src, dst, w, wpos, ssrc, sw);
        // --- layer 1: x1 = A @ x0 (x0 gathered from u/it) ---
        k_spmm1<<<nb4, blk, 0, stream>>>(u, it, off, ssrc, sw, x1);
        // --- layer 2 + epilogue: out = (x0 + x1 + A@x1)/3 ---
        k_spmm2<<<nb4, blk, 0, stream>>>(u, it, off, ssrc, sw, x1, out);
    } else {
        // fallback: atomic scatter path (requires only 76.8 MB ws)
        float* A = (float*)d_ws;
        hipMemsetAsync(out, 0, nd * sizeof(float), stream);
        long long nthreads = (long long)NEDGES * 16;
        int sblocks = (int)((nthreads + 255) / 256);
        scatter_l1<<<sblocks, blk, 0, stream>>>(u, it, out, src, dst, w);
        hipMemsetAsync(A, 0, nd * sizeof(float), stream);
        scatter_gen<<<sblocks, blk, 0, stream>>>(out, A, src, dst, w);
        final_kernel<<<(NNODES * EDIM / 4 + 255) / 256, blk, 0, stream>>>(
            (const float4*)u, (const float4*)it, (const float4*)A, (float4*)out);
    }
}

// Round 3
// 592.771 us; speedup vs baseline: 5.9696x; 1.3450x over previous
//
#include <hip/hip_runtime.h>

#define NUSERS 200000
#define NITEMS 100000
#define NNODES 300000
#define EDIM   64
#define NEDGES 2000000
#define SCAN_NB ((NNODES + 255) / 256)   // 1172 blocks

// ---------------- CSR build (counting sort by dst) ----------------

__global__ void k_hist(const int* __restrict__ dst, int* __restrict__ cnt) {
    int e = blockIdx.x * 256 + threadIdx.x;
    if (e < NEDGES) atomicAdd(&cnt[dst[e]], 1);
}

// in-place exclusive scan of 256-element chunks; block totals to bsum
__global__ void k_scan1(int* __restrict__ data, int* __restrict__ bsum) {
    __shared__ int s[256];
    int i = blockIdx.x * 256 + threadIdx.x;
    int v = (i < NNODES) ? data[i] : 0;
    s[threadIdx.x] = v;
    __syncthreads();
    for (int o = 1; o < 256; o <<= 1) {
        int t = (threadIdx.x >= o) ? s[threadIdx.x - o] : 0;
        __syncthreads();
        s[threadIdx.x] += t;
        __syncthreads();
    }
    if (i < NNODES) data[i] = s[threadIdx.x] - v;          // exclusive
    if (threadIdx.x == 255) bsum[blockIdx.x] = s[255];     // inclusive total
}

// single-block exclusive scan over SCAN_NB block totals (with running carry)
__global__ void k_scan2(int* __restrict__ bsum) {
    __shared__ int s[256];
    __shared__ int carry;
    if (threadIdx.x == 0) carry = 0;
    __syncthreads();
    for (int base = 0; base < SCAN_NB; base += 256) {
        int i = base + threadIdx.x;
        int v = (i < SCAN_NB) ? bsum[i] : 0;
        s[threadIdx.x] = v;
        __syncthreads();
        for (int o = 1; o < 256; o <<= 1) {
            int t = (threadIdx.x >= o) ? s[threadIdx.x - o] : 0;
            __syncthreads();
            s[threadIdx.x] += t;
            __syncthreads();
        }
        if (i < SCAN_NB) bsum[i] = s[threadIdx.x] - v + carry;
        __syncthreads();
        if (threadIdx.x == 0) carry += s[255];
        __syncthreads();
    }
}

__global__ void k_scan3(int* __restrict__ off, const int* __restrict__ bscan,
                        int* __restrict__ wpos) {
    int i = blockIdx.x * 256 + threadIdx.x;
    if (i < NNODES) {
        int v = off[i] + bscan[blockIdx.x];
        off[i] = v;
        wpos[i] = v;
    }
}

// fill packed edge records (src, weight-bits), sorted by dst
__global__ void k_fill(const int* __restrict__ src, const int* __restrict__ dst,
                       const float* __restrict__ w, int* __restrict__ wpos,
                       int2* __restrict__ edata) {
    int e = blockIdx.x * 256 + threadIdx.x;
    if (e < NEDGES) {
        int p = atomicAdd(&wpos[dst[e]], 1);
        edata[p] = make_int2(src[e], __float_as_int(w[e]));
    }
}

// ---------------- gather SpMM ----------------
// One wave per dst node. 4 quarter-waves process 4 edges concurrently (2x
// unrolled -> 8 gathers in flight); each of 16 lanes covers 16 dims (float4).
// Cross-quarter reduce via shfl_xor(16), shfl_xor(32); lanes 0-15 store.

__device__ __forceinline__ float4 row_load_ui(const float4* __restrict__ uq,
                                              const float4* __restrict__ iq,
                                              int s, int l16) {
    const float4* base = (s < NUSERS) ? (uq + (size_t)s * 16)
                                      : (iq + (size_t)(s - NUSERS) * 16);
    return base[l16];
}

__global__ void k_spmm1(const float4* __restrict__ uq, const float4* __restrict__ iq,
                        const int* __restrict__ off, const int2* __restrict__ edata,
                        float4* __restrict__ x1q) {
    int node = blockIdx.x * 4 + (threadIdx.x >> 6);
    if (node >= NNODES) return;
    int lane = threadIdx.x & 63;
    int q = lane >> 4;          // quarter-wave id: which edge slot
    int l16 = lane & 15;        // 16 lanes x float4 = 64 dims
    int p = off[node] + q;
    int end = (node == NNODES - 1) ? NEDGES : off[node + 1];
    float4 a0 = make_float4(0.f, 0.f, 0.f, 0.f);
    float4 a1 = make_float4(0.f, 0.f, 0.f, 0.f);
    // 2x unroll: 8 independent gathers in flight per wave
    for (; p + 4 < end; p += 8) {
        int2 e0 = edata[p];
        int2 e1 = edata[p + 4];
        float4 v0 = row_load_ui(uq, iq, e0.x, l16);
        float4 v1 = row_load_ui(uq, iq, e1.x, l16);
        float w0 = __int_as_float(e0.y), w1 = __int_as_float(e1.y);
        a0.x += w0 * v0.x; a0.y += w0 * v0.y; a0.z += w0 * v0.z; a0.w += w0 * v0.w;
        a1.x += w1 * v1.x; a1.y += w1 * v1.y; a1.z += w1 * v1.z; a1.w += w1 * v1.w;
    }
    if (p < end) {
        int2 e0 = edata[p];
        float4 v0 = row_load_ui(uq, iq, e0.x, l16);
        float w0 = __int_as_float(e0.y);
        a0.x += w0 * v0.x; a0.y += w0 * v0.y; a0.z += w0 * v0.z; a0.w += w0 * v0.w;
    }
    a0.x += a1.x; a0.y += a1.y; a0.z += a1.z; a0.w += a1.w;
    // reduce across the 4 quarter-waves
    a0.x += __shfl_xor(a0.x, 16, 64); a0.y += __shfl_xor(a0.y, 16, 64);
    a0.z += __shfl_xor(a0.z, 16, 64); a0.w += __shfl_xor(a0.w, 16, 64);
    a0.x += __shfl_xor(a0.x, 32, 64); a0.y += __shfl_xor(a0.y, 32, 64);
    a0.z += __shfl_xor(a0.z, 32, 64); a0.w += __shfl_xor(a0.w, 32, 64);
    if (q == 0) x1q[(size_t)node * 16 + l16] = a0;
}

// layer-2 gather fused with final combine: out = (x0 + x1 + A@x1)/3
__global__ void k_spmm2(const float4* __restrict__ uq, const float4* __restrict__ iq,
                        const int* __restrict__ off, const int2* __restrict__ edata,
                        const float4* __restrict__ x1q, float4* __restrict__ outq) {
    int node = blockIdx.x * 4 + (threadIdx.x >> 6);
    if (node >= NNODES) return;
    int lane = threadIdx.x & 63;
    int q = lane >> 4;
    int l16 = lane & 15;
    int p = off[node] + q;
    int end = (node == NNODES - 1) ? NEDGES : off[node + 1];
    float4 a0 = make_float4(0.f, 0.f, 0.f, 0.f);
    float4 a1 = make_float4(0.f, 0.f, 0.f, 0.f);
    for (; p + 4 < end; p += 8) {
        int2 e0 = edata[p];
        int2 e1 = edata[p + 4];
        float4 v0 = x1q[(size_t)e0.x * 16 + l16];
        float4 v1 = x1q[(size_t)e1.x * 16 + l16];
        float w0 = __int_as_float(e0.y), w1 = __int_as_float(e1.y);
        a0.x += w0 * v0.x; a0.y += w0 * v0.y; a0.z += w0 * v0.z; a0.w += w0 * v0.w;
        a1.x += w1 * v1.x; a1.y += w1 * v1.y; a1.z += w1 * v1.z; a1.w += w1 * v1.w;
    }
    if (p < end) {
        int2 e0 = edata[p];
        float4 v0 = x1q[(size_t)e0.x * 16 + l16];
        float w0 = __int_as_float(e0.y);
        a0.x += w0 * v0.x; a0.y += w0 * v0.y; a0.z += w0 * v0.z; a0.w += w0 * v0.w;
    }
    a0.x += a1.x; a0.y += a1.y; a0.z += a1.z; a0.w += a1.w;
    a0.x += __shfl_xor(a0.x, 16, 64); a0.y += __shfl_xor(a0.y, 16, 64);
    a0.z += __shfl_xor(a0.z, 16, 64); a0.w += __shfl_xor(a0.w, 16, 64);
    a0.x += __shfl_xor(a0.x, 32, 64); a0.y += __shfl_xor(a0.y, 32, 64);
    a0.z += __shfl_xor(a0.z, 32, 64); a0.w += __shfl_xor(a0.w, 32, 64);
    if (q == 0) {
        size_t ridx = (size_t)node * 16 + l16;
        float4 x0 = (node < NUSERS) ? uq[ridx] : iq[ridx - (size_t)NUSERS * 16];
        float4 x1v = x1q[ridx];
        const float s = 1.0f / 3.0f;
        float4 r;
        r.x = (x0.x + x1v.x + a0.x) * s;
        r.y = (x0.y + x1v.y + a0.y) * s;
        r.z = (x0.z + x1v.z + a0.z) * s;
        r.w = (x0.w + x1v.w + a0.w) * s;
        outq[ridx] = r;
    }
}

// ---------------- fallback (atomic path, if ws too small) ----------------

__global__ void scatter_l1(const float* __restrict__ u, const float* __restrict__ it,
                           float* __restrict__ y,
                           const int* __restrict__ src, const int* __restrict__ dst,
                           const float* __restrict__ w) {
    long long t = (long long)blockIdx.x * blockDim.x + threadIdx.x;
    int e = (int)(t >> 4);
    if (e >= NEDGES) return;
    int q = (int)(t & 15);
    int s = src[e], d = dst[e];
    float we = w[e];
    const float* xrow = (s < NUSERS) ? (u + (size_t)s * EDIM)
                                     : (it + (size_t)(s - NUSERS) * EDIM);
    float4 v = ((const float4*)xrow)[q];
    float* yp = y + (size_t)d * EDIM + q * 4;
    atomicAdd(yp + 0, we * v.x);
    atomicAdd(yp + 1, we * v.y);
    atomicAdd(yp + 2, we * v.z);
    atomicAdd(yp + 3, we * v.w);
}

__global__ void scatter_gen(const float* __restrict__ x, float* __restrict__ y,
                            const int* __restrict__ src, const int* __restrict__ dst,
                            const float* __restrict__ w) {
    long long t = (long long)blockIdx.x * blockDim.x + threadIdx.x;
    int e = (int)(t >> 4);
    if (e >= NEDGES) return;
    int q = (int)(t & 15);
    int s = src[e], d = dst[e];
    float we = w[e];
    float4 v = ((const float4*)(x + (size_t)s * EDIM))[q];
    float* yp = y + (size_t)d * EDIM + q * 4;
    atomicAdd(yp + 0, we * v.x);
    atomicAdd(yp + 1, we * v.y);
    atomicAdd(yp + 2, we * v.z);
    atomicAdd(yp + 3, we * v.w);
}

__global__ void final_kernel(const float4* __restrict__ u, const float4* __restrict__ it,
                             const float4* __restrict__ x2, float4* __restrict__ outq) {
    int i = blockIdx.x * blockDim.x + threadIdx.x;
    const int uq = NUSERS * EDIM / 4;
    const int nq = NNODES * EDIM / 4;
    if (i >= nq) return;
    float4 x0 = (i < uq) ? u[i] : it[i - uq];
    float4 x1 = outq[i];
    float4 a  = x2[i];
    const float s = 1.0f / 3.0f;
    float4 r;
    r.x = (x0.x + x1.x + a.x) * s;
    r.y = (x0.y + x1.y + a.y) * s;
    r.z = (x0.z + x1.z + a.z) * s;
    r.w = (x0.w + x1.w + a.w) * s;
    outq[i] = r;
}

// ---------------- launch ----------------

extern "C" void kernel_launch(void* const* d_in, const int* in_sizes, int n_in,
                              void* d_out, int out_size, void* d_ws, size_t ws_size,
                              hipStream_t stream) {
    const float* u   = (const float*)d_in[0];
    const float* it  = (const float*)d_in[1];
    const int*   src = (const int*)d_in[2];
    const int*   dst = (const int*)d_in[3];
    const float* w   = (const float*)d_in[4];
    float* out = (float*)d_out;

    const size_t nd = (size_t)NNODES * EDIM;

    // ws layout (full path)
    int*   off   = (int*)d_ws;               // NNODES
    int*   wpos  = off + NNODES;             // NNODES
    int*   bscan = wpos + NNODES;            // SCAN_NB (padded to 2048)
    int2*  edata = (int2*)(bscan + 2048);    // NEDGES packed (src, w)
    float* x1    = (float*)(edata + NEDGES); // NNODES*EDIM
    const size_t needed =
        ((size_t)NNODES * 2 + 2048 + (size_t)NEDGES * 2 + nd) * sizeof(int);

    const int eb = (NEDGES + 255) / 256;        // 7813
    const int nb4 = (NNODES + 3) / 4;           // 75000 (one wave per node)
    dim3 blk(256);

    if (ws_size >= needed) {
        // --- CSR build ---
        hipMemsetAsync(off, 0, (size_t)NNODES * sizeof(int), stream);
        k_hist <<<eb, blk, 0, stream>>>(dst, off);
        k_scan1<<<SCAN_NB, blk, 0, stream>>>(off, bscan);
        k_scan2<<<1, blk, 0, stream>>>(bscan);
        k_scan3<<<SCAN_NB, blk, 0, stream>>>(off, bscan, wpos);
        k_fill <<<eb, blk, 0, stream>>>(src, dst, w, wpos, edata);
        // --- layer 1: x1 = A @ x0 ---
        k_spmm1<<<nb4, blk, 0, stream>>>((const float4*)u, (const float4*)it,
                                         off, edata, (float4*)x1);
        // --- layer 2 + epilogue: out = (x0 + x1 + A@x1)/3 ---
        k_spmm2<<<nb4, blk, 0, stream>>>((const float4*)u, (const float4*)it,
                                         off, edata, (const float4*)x1, (float4*)out);
    } else {
        // fallback: atomic scatter path (requires only 76.8 MB ws)
        float* A = (float*)d_ws;
        hipMemsetAsync(out, 0, nd * sizeof(float), stream);
        long long nthreads = (long long)NEDGES * 16;
        int sblocks = (int)((nthreads + 255) / 256);
        scatter_l1<<<sblocks, blk, 0, stream>>>(u, it, out, src, dst, w);
        hipMemsetAsync(A, 0, nd * sizeof(float), stream);
        scatter_gen<<<sblocks, blk, 0, stream>>>(out, A, src, dst, w);
        final_kernel<<<(NNODES * EDIM / 4 + 255) / 256, blk, 0, stream>>>(
            (const float4*)u, (const float4*)it, (const float4*)A, (float4*)out);
    }
}

// Round 4
// 547.119 us; speedup vs baseline: 6.4677x; 1.0834x over previous
//
#include <hip/hip_runtime.h>

#define NUSERS 200000
#define NITEMS 100000
#define NNODES 300000
#define EDIM   64
#define NEDGES 2000000
#define SCAN_NB ((NNODES + 255) / 256)   // 1172 blocks
#define FILL_BLOCKS 2048
#define NPASS 4

// ---------------- CSR build (counting sort by dst) ----------------

__global__ void k_hist(const int* __restrict__ dst, int* __restrict__ cnt) {
    int e = blockIdx.x * 256 + threadIdx.x;
    if (e < NEDGES) atomicAdd(&cnt[dst[e]], 1);
}

// in-place exclusive scan of 256-element chunks; block totals to bsum
__global__ void k_scan1(int* __restrict__ data, int* __restrict__ bsum) {
    __shared__ int s[256];
    int i = blockIdx.x * 256 + threadIdx.x;
    int v = (i < NNODES) ? data[i] : 0;
    s[threadIdx.x] = v;
    __syncthreads();
    for (int o = 1; o < 256; o <<= 1) {
        int t = (threadIdx.x >= o) ? s[threadIdx.x - o] : 0;
        __syncthreads();
        s[threadIdx.x] += t;
        __syncthreads();
    }
    if (i < NNODES) data[i] = s[threadIdx.x] - v;          // exclusive
    if (threadIdx.x == 255) bsum[blockIdx.x] = s[255];     // inclusive total
}

// single-block exclusive scan over SCAN_NB block totals (with running carry)
__global__ void k_scan2(int* __restrict__ bsum) {
    __shared__ int s[256];
    __shared__ int carry;
    if (threadIdx.x == 0) carry = 0;
    __syncthreads();
    for (int base = 0; base < SCAN_NB; base += 256) {
        int i = base + threadIdx.x;
        int v = (i < SCAN_NB) ? bsum[i] : 0;
        s[threadIdx.x] = v;
        __syncthreads();
        for (int o = 1; o < 256; o <<= 1) {
            int t = (threadIdx.x >= o) ? s[threadIdx.x - o] : 0;
            __syncthreads();
            s[threadIdx.x] += t;
            __syncthreads();
        }
        if (i < SCAN_NB) bsum[i] = s[threadIdx.x] - v + carry;
        __syncthreads();
        if (threadIdx.x == 0) carry += s[255];
        __syncthreads();
    }
}

__global__ void k_scan3(int* __restrict__ off, const int* __restrict__ bscan,
                        int* __restrict__ wpos) {
    int i = blockIdx.x * 256 + threadIdx.x;
    if (i < NNODES) {
        int v = off[i] + bscan[blockIdx.x];
        off[i] = v;
        wpos[i] = v;
    }
}

// Windowed fill: persistent grid; pass k only handles dst in window k so that
// concurrent scattered stores cluster into an L2-resident ~4MB edata region
// and coalesce into full cache lines (round-3 single-pass version wrote back
// a 64B line per 8B store: WRITE_SIZE 127MB for a 16MB buffer).
__global__ void k_fill_win(const int* __restrict__ src, const int* __restrict__ dst,
                           const float* __restrict__ w, int* __restrict__ wpos,
                           int2* __restrict__ edata) {
    const int W = (NNODES + NPASS - 1) / NPASS;
    for (int k = 0; k < NPASS; ++k) {
        int lo = k * W;
        int hi = lo + W;
        for (int e = blockIdx.x * 256 + threadIdx.x; e < NEDGES;
             e += FILL_BLOCKS * 256) {
            int d = dst[e];
            if (d >= lo && d < hi) {
                int p = atomicAdd(&wpos[d], 1);
                edata[p] = make_int2(src[e], __float_as_int(w[e]));
            }
        }
    }
}

// ---------------- gather SpMM ----------------
// One wave per dst node. 4 quarter-waves process 4 edges concurrently (2x
// unrolled -> 8 gathers in flight); each of 16 lanes covers 16 dims (float4).
// Cross-quarter reduce via shfl_xor(16), shfl_xor(32); lanes 0-15 store.

__device__ __forceinline__ float4 row_load_ui(const float4* __restrict__ uq,
                                              const float4* __restrict__ iq,
                                              int s, int l16) {
    const float4* base = (s < NUSERS) ? (uq + (size_t)s * 16)
                                      : (iq + (size_t)(s - NUSERS) * 16);
    return base[l16];
}

__global__ void k_spmm1(const float4* __restrict__ uq, const float4* __restrict__ iq,
                        const int* __restrict__ off, const int2* __restrict__ edata,
                        float4* __restrict__ x1q) {
    int node = blockIdx.x * 4 + (threadIdx.x >> 6);
    if (node >= NNODES) return;
    int lane = threadIdx.x & 63;
    int q = lane >> 4;          // quarter-wave id: which edge slot
    int l16 = lane & 15;        // 16 lanes x float4 = 64 dims
    int p = off[node] + q;
    int end = (node == NNODES - 1) ? NEDGES : off[node + 1];
    float4 a0 = make_float4(0.f, 0.f, 0.f, 0.f);
    float4 a1 = make_float4(0.f, 0.f, 0.f, 0.f);
    // 2x unroll: 8 independent gathers in flight per wave
    for (; p + 4 < end; p += 8) {
        int2 e0 = edata[p];
        int2 e1 = edata[p + 4];
        float4 v0 = row_load_ui(uq, iq, e0.x, l16);
        float4 v1 = row_load_ui(uq, iq, e1.x, l16);
        float w0 = __int_as_float(e0.y), w1 = __int_as_float(e1.y);
        a0.x += w0 * v0.x; a0.y += w0 * v0.y; a0.z += w0 * v0.z; a0.w += w0 * v0.w;
        a1.x += w1 * v1.x; a1.y += w1 * v1.y; a1.z += w1 * v1.z; a1.w += w1 * v1.w;
    }
    if (p < end) {
        int2 e0 = edata[p];
        float4 v0 = row_load_ui(uq, iq, e0.x, l16);
        float w0 = __int_as_float(e0.y);
        a0.x += w0 * v0.x; a0.y += w0 * v0.y; a0.z += w0 * v0.z; a0.w += w0 * v0.w;
    }
    a0.x += a1.x; a0.y += a1.y; a0.z += a1.z; a0.w += a1.w;
    // reduce across the 4 quarter-waves
    a0.x += __shfl_xor(a0.x, 16, 64); a0.y += __shfl_xor(a0.y, 16, 64);
    a0.z += __shfl_xor(a0.z, 16, 64); a0.w += __shfl_xor(a0.w, 16, 64);
    a0.x += __shfl_xor(a0.x, 32, 64); a0.y += __shfl_xor(a0.y, 32, 64);
    a0.z += __shfl_xor(a0.z, 32, 64); a0.w += __shfl_xor(a0.w, 32, 64);
    if (q == 0) x1q[(size_t)node * 16 + l16] = a0;
}

// layer-2 gather fused with final combine: out = (x0 + x1 + A@x1)/3
__global__ void k_spmm2(const float4* __restrict__ uq, const float4* __restrict__ iq,
                        const int* __restrict__ off, const int2* __restrict__ edata,
                        const float4* __restrict__ x1q, float4* __restrict__ outq) {
    int node = blockIdx.x * 4 + (threadIdx.x >> 6);
    if (node >= NNODES) return;
    int lane = threadIdx.x & 63;
    int q = lane >> 4;
    int l16 = lane & 15;
    int p = off[node] + q;
    int end = (node == NNODES - 1) ? NEDGES : off[node + 1];
    float4 a0 = make_float4(0.f, 0.f, 0.f, 0.f);
    float4 a1 = make_float4(0.f, 0.f, 0.f, 0.f);
    for (; p + 4 < end; p += 8) {
        int2 e0 = edata[p];
        int2 e1 = edata[p + 4];
        float4 v0 = x1q[(size_t)e0.x * 16 + l16];
        float4 v1 = x1q[(size_t)e1.x * 16 + l16];
        float w0 = __int_as_float(e0.y), w1 = __int_as_float(e1.y);
        a0.x += w0 * v0.x; a0.y += w0 * v0.y; a0.z += w0 * v0.z; a0.w += w0 * v0.w;
        a1.x += w1 * v1.x; a1.y += w1 * v1.y; a1.z += w1 * v1.z; a1.w += w1 * v1.w;
    }
    if (p < end) {
        int2 e0 = edata[p];
        float4 v0 = x1q[(size_t)e0.x * 16 + l16];
        float w0 = __int_as_float(e0.y);
        a0.x += w0 * v0.x; a0.y += w0 * v0.y; a0.z += w0 * v0.z; a0.w += w0 * v0.w;
    }
    a0.x += a1.x; a0.y += a1.y; a0.z += a1.z; a0.w += a1.w;
    a0.x += __shfl_xor(a0.x, 16, 64); a0.y += __shfl_xor(a0.y, 16, 64);
    a0.z += __shfl_xor(a0.z, 16, 64); a0.w += __shfl_xor(a0.w, 16, 64);
    a0.x += __shfl_xor(a0.x, 32, 64); a0.y += __shfl_xor(a0.y, 32, 64);
    a0.z += __shfl_xor(a0.z, 32, 64); a0.w += __shfl_xor(a0.w, 32, 64);
    if (q == 0) {
        size_t ridx = (size_t)node * 16 + l16;
        float4 x0 = (node < NUSERS) ? uq[ridx] : iq[ridx - (size_t)NUSERS * 16];
        float4 x1v = x1q[ridx];
        const float s = 1.0f / 3.0f;
        float4 r;
        r.x = (x0.x + x1v.x + a0.x) * s;
        r.y = (x0.y + x1v.y + a0.y) * s;
        r.z = (x0.z + x1v.z + a0.z) * s;
        r.w = (x0.w + x1v.w + a0.w) * s;
        outq[ridx] = r;
    }
}

// ---------------- fallback (atomic path, if ws too small) ----------------

__global__ void scatter_l1(const float* __restrict__ u, const float* __restrict__ it,
                           float* __restrict__ y,
                           const int* __restrict__ src, const int* __restrict__ dst,
                           const float* __restrict__ w) {
    long long t = (long long)blockIdx.x * blockDim.x + threadIdx.x;
    int e = (int)(t >> 4);
    if (e >= NEDGES) return;
    int q = (int)(t & 15);
    int s = src[e], d = dst[e];
    float we = w[e];
    const float* xrow = (s < NUSERS) ? (u + (size_t)s * EDIM)
                                     : (it + (size_t)(s - NUSERS) * EDIM);
    float4 v = ((const float4*)xrow)[q];
    float* yp = y + (size_t)d * EDIM + q * 4;
    atomicAdd(yp + 0, we * v.x);
    atomicAdd(yp + 1, we * v.y);
    atomicAdd(yp + 2, we * v.z);
    atomicAdd(yp + 3, we * v.w);
}

__global__ void scatter_gen(const float* __restrict__ x, float* __restrict__ y,
                            const int* __restrict__ src, const int* __restrict__ dst,
                            const float* __restrict__ w) {
    long long t = (long long)blockIdx.x * blockDim.x + threadIdx.x;
    int e = (int)(t >> 4);
    if (e >= NEDGES) return;
    int q = (int)(t & 15);
    int s = src[e], d = dst[e];
    float we = w[e];
    float4 v = ((const float4*)(x + (size_t)s * EDIM))[q];
    float* yp = y + (size_t)d * EDIM + q * 4;
    atomicAdd(yp + 0, we * v.x);
    atomicAdd(yp + 1, we * v.y);
    atomicAdd(yp + 2, we * v.z);
    atomicAdd(yp + 3, we * v.w);
}

__global__ void final_kernel(const float4* __restrict__ u, const float4* __restrict__ it,
                             const float4* __restrict__ x2, float4* __restrict__ outq) {
    int i = blockIdx.x * blockDim.x + threadIdx.x;
    const int uq = NUSERS * EDIM / 4;
    const int nq = NNODES * EDIM / 4;
    if (i >= nq) return;
    float4 x0 = (i < uq) ? u[i] : it[i - uq];
    float4 x1 = outq[i];
    float4 a  = x2[i];
    const float s = 1.0f / 3.0f;
    float4 r;
    r.x = (x0.x + x1.x + a.x) * s;
    r.y = (x0.y + x1.y + a.y) * s;
    r.z = (x0.z + x1.z + a.z) * s;
    r.w = (x0.w + x1.w + a.w) * s;
    outq[i] = r;
}

// ---------------- launch ----------------

extern "C" void kernel_launch(void* const* d_in, const int* in_sizes, int n_in,
                              void* d_out, int out_size, void* d_ws, size_t ws_size,
                              hipStream_t stream) {
    const float* u   = (const float*)d_in[0];
    const float* it  = (const float*)d_in[1];
    const int*   src = (const int*)d_in[2];
    const int*   dst = (const int*)d_in[3];
    const float* w   = (const float*)d_in[4];
    float* out = (float*)d_out;

    const size_t nd = (size_t)NNODES * EDIM;

    // ws layout (full path)
    int*   off   = (int*)d_ws;               // NNODES
    int*   wpos  = off + NNODES;             // NNODES
    int*   bscan = wpos + NNODES;            // SCAN_NB (padded to 2048)
    int2*  edata = (int2*)(bscan + 2048);    // NEDGES packed (src, w)
    float* x1    = (float*)(edata + NEDGES); // NNODES*EDIM
    const size_t needed =
        ((size_t)NNODES * 2 + 2048 + (size_t)NEDGES * 2 + nd) * sizeof(int);

    const int eb = (NEDGES + 255) / 256;        // 7813
    const int nb4 = (NNODES + 3) / 4;           // 75000 (one wave per node)
    dim3 blk(256);

    if (ws_size >= needed) {
        // --- CSR build ---
        hipMemsetAsync(off, 0, (size_t)NNODES * sizeof(int), stream);
        k_hist <<<eb, blk, 0, stream>>>(dst, off);
        k_scan1<<<SCAN_NB, blk, 0, stream>>>(off, bscan);
        k_scan2<<<1, blk, 0, stream>>>(bscan);
        k_scan3<<<SCAN_NB, blk, 0, stream>>>(off, bscan, wpos);
        k_fill_win<<<FILL_BLOCKS, blk, 0, stream>>>(src, dst, w, wpos, edata);
        // --- layer 1: x1 = A @ x0 ---
        k_spmm1<<<nb4, blk, 0, stream>>>((const float4*)u, (const float4*)it,
                                         off, edata, (float4*)x1);
        // --- layer 2 + epilogue: out = (x0 + x1 + A@x1)/3 ---
        k_spmm2<<<nb4, blk, 0, stream>>>((const float4*)u, (const float4*)it,
                                         off, edata, (const float4*)x1, (float4*)out);
    } else {
        // fallback: atomic scatter path (requires only 76.8 MB ws)
        float* A = (float*)d_ws;
        hipMemsetAsync(out, 0, nd * sizeof(float), stream);
        long long nthreads = (long long)NEDGES * 16;
        int sblocks = (int)((nthreads + 255) / 256);
        scatter_l1<<<sblocks, blk, 0, stream>>>(u, it, out, src, dst, w);
        hipMemsetAsync(A, 0, nd * sizeof(float), stream);
        scatter_gen<<<sblocks, blk, 0, stream>>>(out, A, src, dst, w);
        final_kernel<<<(NNODES * EDIM / 4 + 255) / 256, blk, 0, stream>>>(
            (const float4*)u, (const float4*)it, (const float4*)A, (float4*)out);
    }
}

// Round 5
// 528.000 us; speedup vs baseline: 6.7019x; 1.0362x over previous
//
#include <hip/hip_runtime.h>
#include <hip/hip_bf16.h>

#define NUSERS 200000
#define NITEMS 100000
#define NNODES 300000
#define EDIM   64
#define NEDGES 2000000
#define SCAN_NB ((NNODES + 255) / 256)   // 1172 blocks
#define FILL_BLOCKS 2048
#define NPASS 4

typedef unsigned short u16;

__device__ __forceinline__ float bf2f(u16 h) {
    return __uint_as_float((unsigned)h << 16);
}
__device__ __forceinline__ u16 f2bf(float f) {
    union { __hip_bfloat16 b; u16 u; } c;
    c.b = __float2bfloat16(f);   // RNE
    return c.u;
}

// ---------------- CSR build (counting sort by dst) ----------------

__global__ void k_hist(const int4* __restrict__ dst4, int* __restrict__ cnt) {
    int i = blockIdx.x * 256 + threadIdx.x;
    if (i < NEDGES / 4) {
        int4 d = dst4[i];
        atomicAdd(&cnt[d.x], 1);
        atomicAdd(&cnt[d.y], 1);
        atomicAdd(&cnt[d.z], 1);
        atomicAdd(&cnt[d.w], 1);
    }
}

// in-place exclusive scan of 256-element chunks; block totals to bsum
__global__ void k_scan1(int* __restrict__ data, int* __restrict__ bsum) {
    __shared__ int s[256];
    int i = blockIdx.x * 256 + threadIdx.x;
    int v = (i < NNODES) ? data[i] : 0;
    s[threadIdx.x] = v;
    __syncthreads();
    for (int o = 1; o < 256; o <<= 1) {
        int t = (threadIdx.x >= o) ? s[threadIdx.x - o] : 0;
        __syncthreads();
        s[threadIdx.x] += t;
        __syncthreads();
    }
    if (i < NNODES) data[i] = s[threadIdx.x] - v;          // exclusive
    if (threadIdx.x == 255) bsum[blockIdx.x] = s[255];     // inclusive total
}

// single-block exclusive scan over SCAN_NB block totals (with running carry)
__global__ void k_scan2(int* __restrict__ bsum) {
    __shared__ int s[256];
    __shared__ int carry;
    if (threadIdx.x == 0) carry = 0;
    __syncthreads();
    for (int base = 0; base < SCAN_NB; base += 256) {
        int i = base + threadIdx.x;
        int v = (i < SCAN_NB) ? bsum[i] : 0;
        s[threadIdx.x] = v;
        __syncthreads();
        for (int o = 1; o < 256; o <<= 1) {
            int t = (threadIdx.x >= o) ? s[threadIdx.x - o] : 0;
            __syncthreads();
            s[threadIdx.x] += t;
            __syncthreads();
        }
        if (i < SCAN_NB) bsum[i] = s[threadIdx.x] - v + carry;
        __syncthreads();
        if (threadIdx.x == 0) carry += s[255];
        __syncthreads();
    }
}

__global__ void k_scan3(int* __restrict__ off, const int* __restrict__ bscan,
                        int* __restrict__ wpos) {
    int i = blockIdx.x * 256 + threadIdx.x;
    if (i < NNODES) {
        int v = off[i] + bscan[blockIdx.x];
        off[i] = v;
        wpos[i] = v;
    }
}

// Windowed fill: pass k only handles dst in window k so concurrent scattered
// stores cluster into a small edata region and coalesce into full L2 lines.
__global__ void k_fill_win(const int* __restrict__ src, const int4* __restrict__ dst4,
                           const float* __restrict__ w, int* __restrict__ wpos,
                           int2* __restrict__ edata) {
    const int W = (NNODES + NPASS - 1) / NPASS;
    for (int k = 0; k < NPASS; ++k) {
        int lo = k * W;
        int hi = lo + W;
        for (int i = blockIdx.x * 256 + threadIdx.x; i < NEDGES / 4;
             i += FILL_BLOCKS * 256) {
            int4 d = dst4[i];
            int e = i * 4;
            if (d.x >= lo && d.x < hi) {
                int p = atomicAdd(&wpos[d.x], 1);
                edata[p] = make_int2(src[e], __float_as_int(w[e]));
            }
            if (d.y >= lo && d.y < hi) {
                int p = atomicAdd(&wpos[d.y], 1);
                edata[p] = make_int2(src[e + 1], __float_as_int(w[e + 1]));
            }
            if (d.z >= lo && d.z < hi) {
                int p = atomicAdd(&wpos[d.z], 1);
                edata[p] = make_int2(src[e + 2], __float_as_int(w[e + 2]));
            }
            if (d.w >= lo && d.w < hi) {
                int p = atomicAdd(&wpos[d.w], 1);
                edata[p] = make_int2(src[e + 3], __float_as_int(w[e + 3]));
            }
        }
    }
}

// ---------------- bf16 conversion: [u; it] fp32 -> xb bf16 ----------------
// One thread per float4 (4 dims): read 16B fp32, write 8B bf16.
__global__ void k_convert(const float4* __restrict__ uq, const float4* __restrict__ iq,
                          ushort4* __restrict__ xb4) {
    int i = blockIdx.x * 256 + threadIdx.x;
    const int uq_n = NUSERS * 16;
    const int nq_n = NNODES * 16;
    if (i >= nq_n) return;
    float4 v = (i < uq_n) ? uq[i] : iq[i - uq_n];
    ushort4 h;
    h.x = f2bf(v.x); h.y = f2bf(v.y); h.z = f2bf(v.z); h.w = f2bf(v.w);
    xb4[i] = h;
}

// ---------------- gather SpMM (bf16 rows, fp32 accumulate) ----------------
// One wave per dst node. 4 quarter-waves process 4 edges concurrently (2x
// unrolled -> 8 gathers in flight); 16 lanes x ushort4 = 64 bf16 dims = 128B row.
// Cross-quarter reduce via shfl_xor(16), shfl_xor(32); lanes 0-15 store.

__device__ __forceinline__ float4 bfrow(const ushort4* __restrict__ xb4, int s, int l16) {
    ushort4 h = xb4[(size_t)s * 16 + l16];
    float4 v;
    v.x = bf2f(h.x); v.y = bf2f(h.y); v.z = bf2f(h.z); v.w = bf2f(h.w);
    return v;
}

// layer 1: x1b = bf16(A @ xb)
__global__ void k_spmm1(const ushort4* __restrict__ xb4,
                        const int* __restrict__ off, const int2* __restrict__ edata,
                        ushort4* __restrict__ x1b4) {
    int node = blockIdx.x * 4 + (threadIdx.x >> 6);
    if (node >= NNODES) return;
    int lane = threadIdx.x & 63;
    int q = lane >> 4;          // quarter-wave id: edge slot
    int l16 = lane & 15;        // 16 lanes x 4 dims
    int p = off[node] + q;
    int end = (node == NNODES - 1) ? NEDGES : off[node + 1];
    float4 a0 = make_float4(0.f, 0.f, 0.f, 0.f);
    float4 a1 = make_float4(0.f, 0.f, 0.f, 0.f);
    for (; p + 4 < end; p += 8) {
        int2 e0 = edata[p];
        int2 e1 = edata[p + 4];
        float4 v0 = bfrow(xb4, e0.x, l16);
        float4 v1 = bfrow(xb4, e1.x, l16);
        float w0 = __int_as_float(e0.y), w1 = __int_as_float(e1.y);
        a0.x += w0 * v0.x; a0.y += w0 * v0.y; a0.z += w0 * v0.z; a0.w += w0 * v0.w;
        a1.x += w1 * v1.x; a1.y += w1 * v1.y; a1.z += w1 * v1.z; a1.w += w1 * v1.w;
    }
    if (p < end) {
        int2 e0 = edata[p];
        float4 v0 = bfrow(xb4, e0.x, l16);
        float w0 = __int_as_float(e0.y);
        a0.x += w0 * v0.x; a0.y += w0 * v0.y; a0.z += w0 * v0.z; a0.w += w0 * v0.w;
    }
    a0.x += a1.x; a0.y += a1.y; a0.z += a1.z; a0.w += a1.w;
    a0.x += __shfl_xor(a0.x, 16, 64); a0.y += __shfl_xor(a0.y, 16, 64);
    a0.z += __shfl_xor(a0.z, 16, 64); a0.w += __shfl_xor(a0.w, 16, 64);
    a0.x += __shfl_xor(a0.x, 32, 64); a0.y += __shfl_xor(a0.y, 32, 64);
    a0.z += __shfl_xor(a0.z, 32, 64); a0.w += __shfl_xor(a0.w, 32, 64);
    if (q == 0) {
        ushort4 h;
        h.x = f2bf(a0.x); h.y = f2bf(a0.y); h.z = f2bf(a0.z); h.w = f2bf(a0.w);
        x1b4[(size_t)node * 16 + l16] = h;
    }
}

// layer 2 fused with epilogue: out = (x0_fp32 + x1b + A@x1b)/3
__global__ void k_spmm2(const float4* __restrict__ uq, const float4* __restrict__ iq,
                        const ushort4* __restrict__ x1b4,
                        const int* __restrict__ off, const int2* __restrict__ edata,
                        float4* __restrict__ outq) {
    int node = blockIdx.x * 4 + (threadIdx.x >> 6);
    if (node >= NNODES) return;
    int lane = threadIdx.x & 63;
    int q = lane >> 4;
    int l16 = lane & 15;
    int p = off[node] + q;
    int end = (node == NNODES - 1) ? NEDGES : off[node + 1];
    float4 a0 = make_float4(0.f, 0.f, 0.f, 0.f);
    float4 a1 = make_float4(0.f, 0.f, 0.f, 0.f);
    for (; p + 4 < end; p += 8) {
        int2 e0 = edata[p];
        int2 e1 = edata[p + 4];
        float4 v0 = bfrow(x1b4, e0.x, l16);
        float4 v1 = bfrow(x1b4, e1.x, l16);
        float w0 = __int_as_float(e0.y), w1 = __int_as_float(e1.y);
        a0.x += w0 * v0.x; a0.y += w0 * v0.y; a0.z += w0 * v0.z; a0.w += w0 * v0.w;
        a1.x += w1 * v1.x; a1.y += w1 * v1.y; a1.z += w1 * v1.z; a1.w += w1 * v1.w;
    }
    if (p < end) {
        int2 e0 = edata[p];
        float4 v0 = bfrow(x1b4, e0.x, l16);
        float w0 = __int_as_float(e0.y);
        a0.x += w0 * v0.x; a0.y += w0 * v0.y; a0.z += w0 * v0.z; a0.w += w0 * v0.w;
    }
    a0.x += a1.x; a0.y += a1.y; a0.z += a1.z; a0.w += a1.w;
    a0.x += __shfl_xor(a0.x, 16, 64); a0.y += __shfl_xor(a0.y, 16, 64);
    a0.z += __shfl_xor(a0.z, 16, 64); a0.w += __shfl_xor(a0.w, 16, 64);
    a0.x += __shfl_xor(a0.x, 32, 64); a0.y += __shfl_xor(a0.y, 32, 64);
    a0.z += __shfl_xor(a0.z, 32, 64); a0.w += __shfl_xor(a0.w, 32, 64);
    if (q == 0) {
        size_t ridx = (size_t)node * 16 + l16;
        float4 x0 = (node < NUSERS) ? uq[ridx] : iq[ridx - (size_t)NUSERS * 16];
        float4 x1v = bfrow(x1b4, node, l16);
        const float s = 1.0f / 3.0f;
        float4 r;
        r.x = (x0.x + x1v.x + a0.x) * s;
        r.y = (x0.y + x1v.y + a0.y) * s;
        r.z = (x0.z + x1v.z + a0.z) * s;
        r.w = (x0.w + x1v.w + a0.w) * s;
        outq[ridx] = r;
    }
}

// ---------------- fallback (atomic path, if ws too small) ----------------

__global__ void scatter_l1(const float* __restrict__ u, const float* __restrict__ it,
                           float* __restrict__ y,
                           const int* __restrict__ src, const int* __restrict__ dst,
                           const float* __restrict__ w) {
    long long t = (long long)blockIdx.x * blockDim.x + threadIdx.x;
    int e = (int)(t >> 4);
    if (e >= NEDGES) return;
    int q = (int)(t & 15);
    int s = src[e], d = dst[e];
    float we = w[e];
    const float* xrow = (s < NUSERS) ? (u + (size_t)s * EDIM)
                                     : (it + (size_t)(s - NUSERS) * EDIM);
    float4 v = ((const float4*)xrow)[q];
    float* yp = y + (size_t)d * EDIM + q * 4;
    atomicAdd(yp + 0, we * v.x);
    atomicAdd(yp + 1, we * v.y);
    atomicAdd(yp + 2, we * v.z);
    atomicAdd(yp + 3, we * v.w);
}

__global__ void scatter_gen(const float* __restrict__ x, float* __restrict__ y,
                            const int* __restrict__ src, const int* __restrict__ dst,
                            const float* __restrict__ w) {
    long long t = (long long)blockIdx.x * blockDim.x + threadIdx.x;
    int e = (int)(t >> 4);
    if (e >= NEDGES) return;
    int q = (int)(t & 15);
    int s = src[e], d = dst[e];
    float we = w[e];
    float4 v = ((const float4*)(x + (size_t)s * EDIM))[q];
    float* yp = y + (size_t)d * EDIM + q * 4;
    atomicAdd(yp + 0, we * v.x);
    atomicAdd(yp + 1, we * v.y);
    atomicAdd(yp + 2, we * v.z);
    atomicAdd(yp + 3, we * v.w);
}

__global__ void final_kernel(const float4* __restrict__ u, const float4* __restrict__ it,
                             const float4* __restrict__ x2, float4* __restrict__ outq) {
    int i = blockIdx.x * blockDim.x + threadIdx.x;
    const int uq = NUSERS * EDIM / 4;
    const int nq = NNODES * EDIM / 4;
    if (i >= nq) return;
    float4 x0 = (i < uq) ? u[i] : it[i - uq];
    float4 x1 = outq[i];
    float4 a  = x2[i];
    const float s = 1.0f / 3.0f;
    float4 r;
    r.x = (x0.x + x1.x + a.x) * s;
    r.y = (x0.y + x1.y + a.y) * s;
    r.z = (x0.z + x1.z + a.z) * s;
    r.w = (x0.w + x1.w + a.w) * s;
    outq[i] = r;
}

// ---------------- launch ----------------

extern "C" void kernel_launch(void* const* d_in, const int* in_sizes, int n_in,
                              void* d_out, int out_size, void* d_ws, size_t ws_size,
                              hipStream_t stream) {
    const float* u   = (const float*)d_in[0];
    const float* it  = (const float*)d_in[1];
    const int*   src = (const int*)d_in[2];
    const int*   dst = (const int*)d_in[3];
    const float* w   = (const float*)d_in[4];
    float* out = (float*)d_out;

    const size_t nd = (size_t)NNODES * EDIM;

    // ws layout (full path)
    int*     off   = (int*)d_ws;                 // NNODES
    int*     wpos  = off + NNODES;               // NNODES
    int*     bscan = wpos + NNODES;              // 2048 (>= SCAN_NB)
    int2*    edata = (int2*)(bscan + 2048);      // NEDGES packed (src, w)
    ushort4* xb4   = (ushort4*)(edata + NEDGES); // NNODES*16 (bf16 x0)
    ushort4* x1b4  = xb4 + (size_t)NNODES * 16;  // NNODES*16 (bf16 x1)
    const size_t needed =
        ((size_t)NNODES * 2 + 2048 + (size_t)NEDGES * 2 +
         (size_t)NNODES * 32 * 2) * sizeof(int) / 1 ;  // ints: off,wpos,bscan,edata + 2 bf16 tables

    const int eb4 = (NEDGES / 4 + 255) / 256;   // 1954
    const int nb4 = (NNODES + 3) / 4;           // 75000 (one wave per node)
    const int cb  = (NNODES * 16 + 255) / 256;  // 18750
    dim3 blk(256);

    if (ws_size >= needed) {
        // --- CSR build ---
        hipMemsetAsync(off, 0, (size_t)NNODES * sizeof(int), stream);
        k_hist <<<eb4, blk, 0, stream>>>((const int4*)dst, off);
        k_scan1<<<SCAN_NB, blk, 0, stream>>>(off, bscan);
        k_scan2<<<1, blk, 0, stream>>>(bscan);
        k_scan3<<<SCAN_NB, blk, 0, stream>>>(off, bscan, wpos);
        k_fill_win<<<FILL_BLOCKS, blk, 0, stream>>>(src, (const int4*)dst, w, wpos, edata);
        // --- bf16 table ---
        k_convert<<<cb, blk, 0, stream>>>((const float4*)u, (const float4*)it, xb4);
        // --- layer 1: x1b = bf16(A @ xb) ---
        k_spmm1<<<nb4, blk, 0, stream>>>(xb4, off, edata, x1b4);
        // --- layer 2 + epilogue: out = (x0 + x1 + A@x1)/3 ---
        k_spmm2<<<nb4, blk, 0, stream>>>((const float4*)u, (const float4*)it,
                                         x1b4, off, edata, (float4*)out);
    } else {
        // fallback: atomic scatter path (requires only 76.8 MB ws)
        float* A = (float*)d_ws;
        hipMemsetAsync(out, 0, nd * sizeof(float), stream);
        long long nthreads = (long long)NEDGES * 16;
        int sblocks = (int)((nthreads + 255) / 256);
        scatter_l1<<<sblocks, blk, 0, stream>>>(u, it, out, src, dst, w);
        hipMemsetAsync(A, 0, nd * sizeof(float), stream);
        scatter_gen<<<sblocks, blk, 0, stream>>>(out, A, src, dst, w);
        final_kernel<<<(NNODES * EDIM / 4 + 255) / 256, blk, 0, stream>>>(
            (const float4*)u, (const float4*)it, (const float4*)A, (float4*)out);
    }
}